// Round 9
// baseline (687.221 us; speedup 1.0000x reference)
//
#include <hip/hip_runtime.h>
#include <stdint.h>

#define TT   500
#define BB   64
#define IND  256
#define HD   512
#define OD   35

typedef __attribute__((ext_vector_type(4))) int i32x4;

// fp32 scale exactly as numpy computes it
#define SCALE_F ((float)((1.0 - 0.001) / 31.0))
#define AGT __HIP_MEMORY_SCOPE_AGENT

__device__ __forceinline__ void ast32(void* p, uint32_t v) {
  __hip_atomic_store((uint32_t*)p, v, __ATOMIC_RELAXED, AGT);
}
__device__ __forceinline__ void aadd(int* p, int v) {
  (void)__hip_atomic_fetch_add(p, v, __ATOMIC_RELAXED, AGT);
}
__device__ __forceinline__ int apoll(const int* p) {
  return __hip_atomic_load((int*)p, __ATOMIC_RELAXED, AGT);
}
__device__ __forceinline__ void waitflag(const int* f, int want) {
  while (apoll(f) < want) __builtin_amdgcn_s_sleep(8);
  asm volatile("" ::: "memory");
}
__device__ __forceinline__ void acq_fence() {
  __builtin_amdgcn_fence(__ATOMIC_ACQUIRE, "agent");
}

__device__ __forceinline__ void load16_lds(const int8_t* g, int8_t* l) {
  __builtin_amdgcn_global_load_lds((const __attribute__((address_space(1))) void*)g,
                                   (__attribute__((address_space(3))) void*)l, 16, 0, 0);
}

// ---------------------------------------------------------------- prep + cochlea
// prep blocks (0..2687): weight quant + zero n1..n3+flags (96192 ints).
// cochlea blocks (2688..2751): zero own n_ch rows, then 500-step LIF.
__global__ __launch_bounds__(256) void k_prep_cochlea(const float* __restrict__ W1,
                                                      const float* __restrict__ W2,
                                                      const float* __restrict__ W3,
                                                      const float* __restrict__ W4,
                                                      int8_t* __restrict__ wk1,
                                                      int8_t* __restrict__ wk2,
                                                      int8_t* __restrict__ wk3,
                                                      int8_t* __restrict__ wk4,
                                                      const float* __restrict__ x,
                                                      const float* __restrict__ Wch,
                                                      const float* __restrict__ cbetas,
                                                      int8_t* __restrict__ chs,
                                                      int* __restrict__ n_ch,
                                                      int* __restrict__ nz) {
  __shared__ float xs[TT];
  if (blockIdx.x < 2688) {
    int id = blockIdx.x * 256 + threadIdx.x;
    for (int z = id; z < 96192; z += 2688 * 256) nz[z] = 0;   // n1..n3 + flags
    const float* W; int8_t* wk; int idx, K, H;
    if (id < 131072)       { idx = id;          W = W1; wk = wk1; K = 256; H = 512; }
    else if (id < 393216)  { idx = id - 131072; W = W2; wk = wk2; K = 512; H = 512; }
    else if (id < 655360)  { idx = id - 393216; W = W3; wk = wk3; K = 512; H = 512; }
    else                   { idx = id - 655360; W = W4; wk = wk4; K = 512; H = 35;  }
    int h = idx / K;
    int k = idx - h * K;
    int8_t bits = 0;
    if (h < H) {
      float w  = W[h * K + k];
      float wc = fminf(1.0f, fmaxf(0.001f, w));
      float v  = (wc - 0.001f) / SCALE_F;
      float q  = rintf(v);                 // round-half-even, matches np.round; 0..31
      bits = (int8_t)q;
    }
    wk[idx] = bits;
  } else {
    int b = blockIdx.x - 2688;
    int i = threadIdx.x;
    for (int t = threadIdx.x; t < TT; t += 256) {
      n_ch[t * 64 + b] = 0;                // block-exclusive rows; used below only
      xs[t] = x[b * TT + t];
    }
    __syncthreads();
    float w    = Wch[i];
    float beta = fminf(1.0f, fmaxf(0.0f, cbetas[i]));
    float mem  = 0.0f;
    for (int t = 0; t < TT; ++t) {
      float cur = __fmul_rn(xs[t], w);
      int   rs  = (mem > 1.0f);
      float t2  = __fadd_rn(__fmul_rn(beta, mem), cur);
      mem = rs ? __fsub_rn(t2, 1.0f) : t2;
      int spk = (mem > 1.0f);
      int row = t * BB + b;
      chs[(size_t)row * IND + i] = (int8_t)spk;
      unsigned long long bal = __ballot(spk);
      if ((threadIdx.x & 63) == 0) atomicAdd(n_ch + row, (int)__popcll(bal));
    }
  }
}

// ---------------------------------------------------------------- fused layer body (r8-verified)
// One block = batch b x 64-col slice h0. Per 64-t batch: 4-wave i8 MFMA from
// swizzled LDS -> pm in LDS -> barrier -> async next-A stage -> wave0 serial LIF
// (quarters of 16, 1-quarter load lookahead). sbuf spikes written via packed
// agent-scope atomic stores (cross-XCD visible without L2 flush).
template<int K, bool LAST>
__device__ __forceinline__ void run_layer(const int8_t* A, const int8_t* Bw,
                                          const int* nprev, const float* pbeta,
                                          float* spk_out, int8_t* s_out,
                                          int* n_out, float* mem_out,
                                          int b, int h0,
                                          int8_t* As, int8_t* Bs,
                                          uint16_t (*pm)[68], int* nbuf) {
  constexpr int CH = K / 16;                 // 16-B chunks per row (32 or 16)
  int tid = threadIdx.x, lane = tid & 63, w = tid >> 6;
  float beta = fminf(1.0f, fmaxf(0.0f, *pbeta));
  // stage B slice [64][K], XOR-swizzled (slot sl holds chunk (sl&~7)|((sl&7)^(row&7)))
#pragma unroll
  for (int i = 0; i < CH / 4; ++i) {
    int L = i * 256 + tid;
    int row = L / CH, sl = L % CH;
    int kg = (sl & ~7) | ((sl & 7) ^ (row & 7));
    load16_lds(Bw + (size_t)(h0 + row) * K + kg * 16, &Bs[(i * 256 + w * 64) * 16]);
  }
  // stage A batch 0 (rows r -> global row r*64+b)
#pragma unroll
  for (int i = 0; i < CH / 4; ++i) {
    int L = i * 256 + tid;
    int r = L / CH, sl = L % CH;
    int kg = (sl & ~7) | ((sl & 7) ^ (r & 7));
    load16_lds(A + ((size_t)r * 64 + b) * K + kg * 16, &As[(i * 256 + w * 64) * 16]);
  }
  __syncthreads();
  const double DSCALE = (double)SCALE_F;
  const double DWMIN  = (double)0.001f;
  float mem = 0.0f;
  int lr = lane & 15, lk = lane >> 4;
  int arow = w * 16 + lr;
  for (int g = 0; g < 8; ++g) {
    if (w == 1) {
      int t = g * 64 + lane; if (t > 499) t = 499;
      nbuf[lane] = nprev[t * 64 + b];
    }
    i32x4 acc0 = {0,0,0,0}, acc1 = {0,0,0,0}, acc2 = {0,0,0,0}, acc3 = {0,0,0,0};
#pragma unroll
    for (int ks = 0; ks < K / 64; ++ks) {
      int kc = ks * 4 + lk;
      int s0 = (kc & ~7) | ((kc & 7) ^ (lr & 7));     // shared slot (arow&7==brow&7==lr&7)
      i32x4 av  = *(const i32x4*)&As[arow * K + s0 * 16];
      i32x4 bv0 = *(const i32x4*)&Bs[(0 * 16 + lr) * K + s0 * 16];
      i32x4 bv1 = *(const i32x4*)&Bs[(1 * 16 + lr) * K + s0 * 16];
      i32x4 bv2 = *(const i32x4*)&Bs[(2 * 16 + lr) * K + s0 * 16];
      i32x4 bv3 = *(const i32x4*)&Bs[(3 * 16 + lr) * K + s0 * 16];
      acc0 = __builtin_amdgcn_mfma_i32_16x16x64_i8(av, bv0, acc0, 0, 0, 0);
      acc1 = __builtin_amdgcn_mfma_i32_16x16x64_i8(av, bv1, acc1, 0, 0, 0);
      acc2 = __builtin_amdgcn_mfma_i32_16x16x64_i8(av, bv2, acc2, 0, 0, 0);
      acc3 = __builtin_amdgcn_mfma_i32_16x16x64_i8(av, bv3, acc3, 0, 0, 0);
    }
    int pr = w * 16 + lk * 4;
#pragma unroll
    for (int i = 0; i < 4; ++i) {
      pm[pr + i][ 0 + lr] = (uint16_t)acc0[i];
      pm[pr + i][16 + lr] = (uint16_t)acc1[i];
      pm[pr + i][32 + lr] = (uint16_t)acc2[i];
      pm[pr + i][48 + lr] = (uint16_t)acc3[i];
    }
    __syncthreads();                 // pm + nbuf ready; As consumed
    if (g < 7) {
#pragma unroll
      for (int i = 0; i < CH / 4; ++i) {
        int L = i * 256 + tid;
        int r = L / CH, sl = L % CH;
        int kg = (sl & ~7) | ((sl & 7) ^ (r & 7));
        int t = (g + 1) * 64 + r; if (t > 499) t = 499;
        load16_lds(A + ((size_t)t * 64 + b) * K + kg * 16, &As[(i * 256 + w * 64) * 16]);
      }
    }
    if (w == 0) {
      float curA[16], curB[16];
#define LOADQ(dst, q)                                                         \
      { _Pragma("unroll") for (int r = 0; r < 16; ++r) {                      \
          int rr = (q) * 16 + r;                                              \
          dst[r] = (float)((double)(int)pm[rr][lane] * DSCALE                 \
                           + (double)nbuf[rr] * DWMIN); } }
#define CHAINQ(src, q)                                                        \
      { _Pragma("unroll") for (int r = 0; r < 16; ++r) {                      \
          int t = g * 64 + (q) * 16 + r;                                      \
          int   rs = (mem > 1.0f);                                            \
          float t2 = __fadd_rn(__fmul_rn(beta, mem), src[r]);                 \
          mem = rs ? __fsub_rn(t2, 1.0f) : t2;                                \
          int spk = (mem > 1.0f);                                             \
          if (t < 500) {                                                      \
            int row = t * 64 + b;                                             \
            if (!LAST) {                                                      \
              __builtin_nontemporal_store(spk ? 1.0f : 0.0f,                  \
                  &spk_out[(size_t)t * 32768 + (b << 9) + h0 + lane]);        \
              int sp1 = __shfl_down(spk, 1);                                  \
              int sp2 = __shfl_down(spk, 2);                                  \
              int sp3 = __shfl_down(spk, 3);                                  \
              if ((lane & 3) == 0)                                            \
                ast32(s_out + ((size_t)row * 512 + h0 + lane),                \
                      (uint32_t)spk | ((uint32_t)sp1 << 8) |                  \
                      ((uint32_t)sp2 << 16) | ((uint32_t)sp3 << 24));         \
              unsigned long long bal = __ballot(spk);                         \
              if (lane == 0) aadd(n_out + row, (int)__popcll(bal));           \
            } else if (lane < OD) {                                           \
              __builtin_nontemporal_store(spk ? 1.0f : 0.0f,                  \
                  &spk_out[(size_t)t * (BB * OD) + b * OD + lane]);           \
              __builtin_nontemporal_store(mem,                                \
                  &mem_out[(size_t)t * (BB * OD) + b * OD + lane]);           \
            }                                                                 \
          } } }
      LOADQ(curA, 0)
      LOADQ(curB, 1)
      CHAINQ(curA, 0)
      LOADQ(curA, 2)
      CHAINQ(curB, 1)
      LOADQ(curB, 3)
      CHAINQ(curA, 2)
      CHAINQ(curB, 3)
#undef LOADQ
#undef CHAINQ
    }
    __syncthreads();                 // As[g+1] staged; pm free for overwrite
  }
}

// intra-group barrier: drain (via __syncthreads' vmcnt(0)) -> bump -> wait -> acquire
__device__ __forceinline__ void sigwait(int* f, int want) {
  __syncthreads();                   // compiler emits s_waitcnt vmcnt(0) before s_barrier
  if (threadIdx.x == 0) { aadd(f, 1); waitflag(f, want); }
  __syncthreads();
  acq_fence();                       // invalidate caches: staging/plain loads see fresh data
}

// ---------------------------------------------------------------- mega kernel: layers 1-4
// 512 blocks x 256 thr, 74.5 KB LDS -> exactly 2 blocks/CU -> all co-resident.
// Group b = blocks {b, 64+b, ..., 448+b}; inter-layer deps are intra-group only.
__global__ __launch_bounds__(256, 2) void k_mega(
    const int8_t* __restrict__ chs, const int8_t* __restrict__ wk1,
    const int8_t* __restrict__ wk2, const int8_t* __restrict__ wk3,
    const int8_t* __restrict__ wk4,
    const int* __restrict__ n_ch, int* n1, int* n2, int* n3,
    const float* __restrict__ b1, const float* __restrict__ b2,
    const float* __restrict__ b3, const float* __restrict__ b4,
    int8_t* sbufA, int8_t* sbufB, int* F,
    float* spk1, float* spk2, float* spk3, float* spk4, float* mem4) {
  __shared__ __align__(16) int8_t Bs[64 * 512];
  __shared__ __align__(16) int8_t As[64 * 512];
  __shared__ uint16_t pm[64][68];
  __shared__ int nbuf[64];
  int b = blockIdx.x & 63, s = blockIdx.x >> 6, h0 = s * 64;

  run_layer<256, false>(chs,   wk1, n_ch, b1, spk1, sbufA, n1, nullptr, b, h0, As, Bs, pm, nbuf);
  sigwait(F + b, 8);
  run_layer<512, false>(sbufA, wk2, n1,   b2, spk2, sbufB, n2, nullptr, b, h0, As, Bs, pm, nbuf);
  sigwait(F + 64 + b, 8);
  run_layer<512, false>(sbufB, wk3, n2,   b3, spk3, sbufA, n3, nullptr, b, h0, As, Bs, pm, nbuf);
  sigwait(F + 128 + b, 8);
  if (s == 0)
    run_layer<512, true>(sbufA, wk4, n3,  b4, spk4, nullptr, nullptr, mem4, b, 0, As, Bs, pm, nbuf);
}

// ---------------------------------------------------------------- launch (2 nodes)
extern "C" void kernel_launch(void* const* d_in, const int* in_sizes, int n_in,
                              void* d_out, int out_size, void* d_ws, size_t ws_size,
                              hipStream_t stream) {
  const float* x      = (const float*)d_in[0];
  const float* Wch    = (const float*)d_in[1];
  const float* W1     = (const float*)d_in[2];
  const float* W2     = (const float*)d_in[3];
  const float* W3     = (const float*)d_in[4];
  const float* W4     = (const float*)d_in[5];
  const float* cbetas = (const float*)d_in[6];
  const float* b1     = (const float*)d_in[7];
  const float* b2     = (const float*)d_in[8];
  const float* b3     = (const float*)d_in[9];
  const float* b4     = (const float*)d_in[10];

  uint8_t* ws = (uint8_t*)d_ws;
  int8_t*   wk1   = (int8_t*)(ws + 0);          // 512*256   = 131072
  int8_t*   wk2   = (int8_t*)(ws + 131072);     // 512*512   = 262144
  int8_t*   wk3   = (int8_t*)(ws + 393216);     // 262144
  int8_t*   wk4   = (int8_t*)(ws + 655360);     // 64*512    = 32768
  int*      n_ch  = (int*)(ws + 688128);        // 32000*4
  int*      n1    = (int*)(ws + 816128);        // n1,n2,n3 contiguous
  int*      n2    = (int*)(ws + 944128);
  int*      n3    = (int*)(ws + 1072128);       // ends 1200128
  int*      F     = (int*)(ws + 1200128);       // 192 flags (zeroed with n1..n3)
  int8_t*   chs   = (int8_t*)(ws + 1201152);    // 32000*256 = 8192000
  int8_t*   sbufA = (int8_t*)(ws + 9393152);    // 32000*512 = 16384000
  int8_t*   sbufB = (int8_t*)(ws + 25777152);   // -> ends 42161152

  float* out  = (float*)d_out;
  float* spk1 = out;                // 500*64*512
  float* spk2 = out + 16384000;
  float* spk3 = out + 32768000;
  float* spk4 = out + 49152000;     // 500*64*35
  float* mem4 = out + 50272000;

  // node 1: prep (+n/flag zeroing) || cochlea (+own n_ch zeroing)
  k_prep_cochlea<<<2752, 256, 0, stream>>>(W1, W2, W3, W4, wk1, wk2, wk3, wk4,
                                           x, Wch, cbetas, chs, n_ch, n1);
  // node 2: all four layers, intra-group flag sync
  k_mega<<<512, 256, 0, stream>>>(chs, wk1, wk2, wk3, wk4,
                                  n_ch, n1, n2, n3,
                                  b1, b2, b3, b4,
                                  sbufA, sbufB, F,
                                  spk1, spk2, spk3, spk4, mem4);
}

// Round 10
// 384.778 us; speedup vs baseline: 1.7860x; 1.7860x over previous
//
#include <hip/hip_runtime.h>
#include <stdint.h>

#define TT   500
#define BB   64
#define IND  256
#define HD   512
#define OD   35

typedef __attribute__((ext_vector_type(4))) int i32x4;

// fp32 scale exactly as numpy computes it
#define SCALE_F ((float)((1.0 - 0.001) / 31.0))

__device__ __forceinline__ void load16_lds(const int8_t* g, int8_t* l) {
  __builtin_amdgcn_global_load_lds((const __attribute__((address_space(1))) void*)g,
                                   (__attribute__((address_space(3))) void*)l, 16, 0, 0);
}

// ---------------------------------------------------------------- prep + cochlea
// prep blocks (0..2687): weight quant. cochlea blocks (2688..2751): LIF scan.
// No spike-count outputs anywhere: consumers compute n from their own A tiles.
__global__ __launch_bounds__(256) void k_prep_cochlea(const float* __restrict__ W1,
                                                      const float* __restrict__ W2,
                                                      const float* __restrict__ W3,
                                                      const float* __restrict__ W4,
                                                      int8_t* __restrict__ wk1,
                                                      int8_t* __restrict__ wk2,
                                                      int8_t* __restrict__ wk3,
                                                      int8_t* __restrict__ wk4,
                                                      const float* __restrict__ x,
                                                      const float* __restrict__ Wch,
                                                      const float* __restrict__ cbetas,
                                                      int8_t* __restrict__ chs) {
  __shared__ float xs[TT];
  if (blockIdx.x < 2688) {
    int id = blockIdx.x * 256 + threadIdx.x;
    const float* W; int8_t* wk; int idx, K, H;
    if (id < 131072)       { idx = id;          W = W1; wk = wk1; K = 256; H = 512; }
    else if (id < 393216)  { idx = id - 131072; W = W2; wk = wk2; K = 512; H = 512; }
    else if (id < 655360)  { idx = id - 393216; W = W3; wk = wk3; K = 512; H = 512; }
    else                   { idx = id - 655360; W = W4; wk = wk4; K = 512; H = 35;  }
    int h = idx / K;
    int k = idx - h * K;
    int8_t bits = 0;
    if (h < H) {
      float w  = W[h * K + k];
      float wc = fminf(1.0f, fmaxf(0.001f, w));
      float v  = (wc - 0.001f) / SCALE_F;
      float q  = rintf(v);                 // round-half-even, matches np.round; 0..31
      bits = (int8_t)q;
    }
    wk[idx] = bits;
  } else {
    int b = blockIdx.x - 2688;
    int i = threadIdx.x;
    for (int t = threadIdx.x; t < TT; t += 256) xs[t] = x[b * TT + t];
    __syncthreads();
    float w    = Wch[i];
    float beta = fminf(1.0f, fmaxf(0.0f, cbetas[i]));
    float mem  = 0.0f;
    for (int t = 0; t < TT; ++t) {
      float cur = __fmul_rn(xs[t], w);
      int   rs  = (mem > 1.0f);
      float t2  = __fadd_rn(__fmul_rn(beta, mem), cur);
      mem = rs ? __fsub_rn(t2, 1.0f) : t2;
      int spk = (mem > 1.0f);
      chs[(size_t)(t * BB + b) * IND + i] = (int8_t)spk;
    }
  }
}

// ---------------------------------------------------------------- fused layer: GEMM + LIF scan
// One block = (batch element b) x (64-col slice h0); b=blk&63 keeps the 8
// slice-blocks of a batch on one XCD (A rows L2-resident). Per 64-t batch:
// 4-wave i8 MFMA from swizzled LDS (+1 ones-column MFMA computing the row
// spike-count n directly from the A tile -> nbuf, no atomics/gather anywhere)
// -> pm in LDS -> barrier -> async next-A stage -> wave0 np-exact serial LIF
// in quarters of 16 with 1-quarter load lookahead (r8-verified).
template<int K, bool LAST>
__global__ __launch_bounds__(256) void k_layer(const int8_t* __restrict__ A,
                                               const int8_t* __restrict__ Bw,
                                               const float* __restrict__ pbeta,
                                               float* __restrict__ spk_out,
                                               int8_t* __restrict__ s_out,
                                               float* __restrict__ mem_out) {
  constexpr int CH = K / 16;                 // 16-B chunks per row (32 or 16)
  __shared__ __align__(16) int8_t Bs[64 * K];
  __shared__ __align__(16) int8_t As[64 * K];
  __shared__ uint16_t pm[64][68];            // +4 pad: conflict-free write/read
  __shared__ int nbuf[64];
  int tid = threadIdx.x, lane = tid & 63, w = tid >> 6;
  int b, h0;
  if (LAST) { b = blockIdx.x;      h0 = 0; }
  else      { b = blockIdx.x & 63; h0 = (blockIdx.x >> 6) * 64; }
  float beta = fminf(1.0f, fmaxf(0.0f, *pbeta));
  // stage B slice [64][K], XOR-swizzled (slot sl holds chunk (sl&~7)|((sl&7)^(row&7)))
#pragma unroll
  for (int i = 0; i < CH / 4; ++i) {
    int L = i * 256 + tid;
    int row = L / CH, sl = L % CH;
    int kg = (sl & ~7) | ((sl & 7) ^ (row & 7));
    load16_lds(Bw + (size_t)(h0 + row) * K + kg * 16, &Bs[(i * 256 + w * 64) * 16]);
  }
  // stage A batch 0 (rows r -> global row r*64+b)
#pragma unroll
  for (int i = 0; i < CH / 4; ++i) {
    int L = i * 256 + tid;
    int r = L / CH, sl = L % CH;
    int kg = (sl & ~7) | ((sl & 7) ^ (r & 7));
    load16_lds(A + ((size_t)r * 64 + b) * K + kg * 16, &As[(i * 256 + w * 64) * 16]);
  }
  __syncthreads();
  const double DSCALE = (double)SCALE_F;
  const double DWMIN  = (double)0.001f;
  float mem = 0.0f;
  int lr = lane & 15, lk = lane >> 4;
  int arow = w * 16 + lr;
  const i32x4 ones = {0x01010101, 0x01010101, 0x01010101, 0x01010101};
  for (int g = 0; g < 8; ++g) {
    i32x4 acc0 = {0,0,0,0}, acc1 = {0,0,0,0}, acc2 = {0,0,0,0}, acc3 = {0,0,0,0};
    i32x4 acc4 = {0,0,0,0};                  // row-sum column (n)
#pragma unroll
    for (int ks = 0; ks < K / 64; ++ks) {
      int kc = ks * 4 + lk;
      int s0 = (kc & ~7) | ((kc & 7) ^ (lr & 7));     // shared slot (arow&7==brow&7==lr&7)
      i32x4 av  = *(const i32x4*)&As[arow * K + s0 * 16];
      i32x4 bv0 = *(const i32x4*)&Bs[(0 * 16 + lr) * K + s0 * 16];
      i32x4 bv1 = *(const i32x4*)&Bs[(1 * 16 + lr) * K + s0 * 16];
      i32x4 bv2 = *(const i32x4*)&Bs[(2 * 16 + lr) * K + s0 * 16];
      i32x4 bv3 = *(const i32x4*)&Bs[(3 * 16 + lr) * K + s0 * 16];
      acc0 = __builtin_amdgcn_mfma_i32_16x16x64_i8(av, bv0, acc0, 0, 0, 0);
      acc1 = __builtin_amdgcn_mfma_i32_16x16x64_i8(av, bv1, acc1, 0, 0, 0);
      acc2 = __builtin_amdgcn_mfma_i32_16x16x64_i8(av, bv2, acc2, 0, 0, 0);
      acc3 = __builtin_amdgcn_mfma_i32_16x16x64_i8(av, bv3, acc3, 0, 0, 0);
      acc4 = __builtin_amdgcn_mfma_i32_16x16x64_i8(av, ones, acc4, 0, 0, 0);
    }
    // pm write: D layout col=lane&15, row=(lane>>4)*4+i (verified, dtype-independent)
    int pr = w * 16 + lk * 4;
#pragma unroll
    for (int i = 0; i < 4; ++i) {
      pm[pr + i][ 0 + lr] = (uint16_t)acc0[i];
      pm[pr + i][16 + lr] = (uint16_t)acc1[i];
      pm[pr + i][32 + lr] = (uint16_t)acc2[i];
      pm[pr + i][48 + lr] = (uint16_t)acc3[i];
      if (lr == 0) nbuf[pr + i] = acc4[i];   // n = row sum (same value in every col)
    }
    __syncthreads();                 // pm + nbuf ready; As consumed
    // all waves: issue next A batch (async; drains at the trailing barrier)
    if (g < 7) {
#pragma unroll
      for (int i = 0; i < CH / 4; ++i) {
        int L = i * 256 + tid;
        int r = L / CH, sl = L % CH;
        int kg = (sl & ~7) | ((sl & 7) ^ (r & 7));
        int t = (g + 1) * 64 + r; if (t > 499) t = 499;
        load16_lds(A + ((size_t)t * 64 + b) * K + kg * 16, &As[(i * 256 + w * 64) * 16]);
      }
    }
    // wave0: np-exact serial LIF, quarters of 16 with 1-quarter load lookahead.
    if (w == 0) {
      float curA[16], curB[16];
#define LOADQ(dst, q)                                                         \
      { _Pragma("unroll") for (int r = 0; r < 16; ++r) {                      \
          int rr = (q) * 16 + r;                                              \
          dst[r] = (float)((double)(int)pm[rr][lane] * DSCALE                 \
                           + (double)nbuf[rr] * DWMIN); } }
#define CHAINQ(src, q)                                                        \
      { _Pragma("unroll") for (int r = 0; r < 16; ++r) {                      \
          int t = g * 64 + (q) * 16 + r;                                      \
          int   rs = (mem > 1.0f);                                            \
          float t2 = __fadd_rn(__fmul_rn(beta, mem), src[r]);                 \
          mem = rs ? __fsub_rn(t2, 1.0f) : t2;                                \
          int spk = (mem > 1.0f);                                             \
          if (t < 500) {                                                      \
            int row = t * 64 + b;                                             \
            if (!LAST) {                                                      \
              __builtin_nontemporal_store(spk ? 1.0f : 0.0f,                  \
                  &spk_out[(size_t)t * 32768 + (b << 9) + h0 + lane]);        \
              s_out[(size_t)row * 512 + h0 + lane] = (int8_t)spk;             \
            } else if (lane < OD) {                                           \
              __builtin_nontemporal_store(spk ? 1.0f : 0.0f,                  \
                  &spk_out[(size_t)t * (BB * OD) + b * OD + lane]);           \
              __builtin_nontemporal_store(mem,                                \
                  &mem_out[(size_t)t * (BB * OD) + b * OD + lane]);           \
            }                                                                 \
          } } }
      LOADQ(curA, 0)
      LOADQ(curB, 1)
      CHAINQ(curA, 0)
      LOADQ(curA, 2)
      CHAINQ(curB, 1)
      LOADQ(curB, 3)
      CHAINQ(curA, 2)
      CHAINQ(curB, 3)
#undef LOADQ
#undef CHAINQ
    }
    __syncthreads();                 // As[g+1] staged; pm free for overwrite
  }
}

// ---------------------------------------------------------------- launch (5 nodes, no memset)
extern "C" void kernel_launch(void* const* d_in, const int* in_sizes, int n_in,
                              void* d_out, int out_size, void* d_ws, size_t ws_size,
                              hipStream_t stream) {
  const float* x      = (const float*)d_in[0];
  const float* Wch    = (const float*)d_in[1];
  const float* W1     = (const float*)d_in[2];
  const float* W2     = (const float*)d_in[3];
  const float* W3     = (const float*)d_in[4];
  const float* W4     = (const float*)d_in[5];
  const float* cbetas = (const float*)d_in[6];
  const float* b1     = (const float*)d_in[7];
  const float* b2     = (const float*)d_in[8];
  const float* b3     = (const float*)d_in[9];
  const float* b4     = (const float*)d_in[10];

  uint8_t* ws = (uint8_t*)d_ws;
  int8_t*   wk1   = (int8_t*)(ws + 0);          // 512*256   = 131072
  int8_t*   wk2   = (int8_t*)(ws + 131072);     // 512*512   = 262144
  int8_t*   wk3   = (int8_t*)(ws + 393216);     // 262144
  int8_t*   wk4   = (int8_t*)(ws + 655360);     // 64*512    = 32768 -> 688128
  int8_t*   chs   = (int8_t*)(ws + 688128);     // 32000*256 = 8192000
  int8_t*   sbufA = (int8_t*)(ws + 8880128);    // 32000*512 = 16384000
  int8_t*   sbufB = (int8_t*)(ws + 25264128);   // -> ends 41648128

  float* out  = (float*)d_out;
  float* spk1 = out;                // 500*64*512
  float* spk2 = out + 16384000;
  float* spk3 = out + 32768000;
  float* spk4 = out + 49152000;     // 500*64*35
  float* mem4 = out + 50272000;

  // prep (blocks 0..2687) + cochlea (blocks 2688..2751), independent work
  k_prep_cochlea<<<2752, 256, 0, stream>>>(W1, W2, W3, W4, wk1, wk2, wk3, wk4,
                                           x, Wch, cbetas, chs);

  // fused layers: read buffer != write buffer
  k_layer<256, false><<<512, 256, 0, stream>>>(chs,   wk1, b1, spk1, sbufA, nullptr);
  k_layer<512, false><<<512, 256, 0, stream>>>(sbufA, wk2, b2, spk2, sbufB, nullptr);
  k_layer<512, false><<<512, 256, 0, stream>>>(sbufB, wk3, b3, spk3, sbufA, nullptr);
  k_layer<512, true ><<<64,  256, 0, stream>>>(sbufA, wk4, b4, spk4, nullptr, mem4);
}

// Round 11
// 352.830 us; speedup vs baseline: 1.9477x; 1.0905x over previous
//
#include <hip/hip_runtime.h>
#include <stdint.h>

#define TT   500
#define BB   64
#define IND  256
#define HD   512
#define OD   35

typedef __attribute__((ext_vector_type(4))) int i32x4;

// fp32 scale exactly as numpy computes it
#define SCALE_F ((float)((1.0 - 0.001) / 31.0))

__device__ __forceinline__ void load16_lds(const int8_t* g, int8_t* l) {
  __builtin_amdgcn_global_load_lds((const __attribute__((address_space(1))) void*)g,
                                   (__attribute__((address_space(3))) void*)l, 16, 0, 0);
}

// ---------------------------------------------------------------- prep + cochlea
// prep blocks (0..2687): weight quant. cochlea blocks (2688..2751): LIF scan.
// No spike-count outputs anywhere: consumers compute n via a ones-column MFMA.
__global__ __launch_bounds__(256) void k_prep_cochlea(const float* __restrict__ W1,
                                                      const float* __restrict__ W2,
                                                      const float* __restrict__ W3,
                                                      const float* __restrict__ W4,
                                                      int8_t* __restrict__ wk1,
                                                      int8_t* __restrict__ wk2,
                                                      int8_t* __restrict__ wk3,
                                                      int8_t* __restrict__ wk4,
                                                      const float* __restrict__ x,
                                                      const float* __restrict__ Wch,
                                                      const float* __restrict__ cbetas,
                                                      int8_t* __restrict__ chs) {
  __shared__ float xs[TT];
  if (blockIdx.x < 2688) {
    int id = blockIdx.x * 256 + threadIdx.x;
    const float* W; int8_t* wk; int idx, K, H;
    if (id < 131072)       { idx = id;          W = W1; wk = wk1; K = 256; H = 512; }
    else if (id < 393216)  { idx = id - 131072; W = W2; wk = wk2; K = 512; H = 512; }
    else if (id < 655360)  { idx = id - 393216; W = W3; wk = wk3; K = 512; H = 512; }
    else                   { idx = id - 655360; W = W4; wk = wk4; K = 512; H = 35;  }
    int h = idx / K;
    int k = idx - h * K;
    int8_t bits = 0;
    if (h < H) {
      float w  = W[h * K + k];
      float wc = fminf(1.0f, fmaxf(0.001f, w));
      float v  = (wc - 0.001f) / SCALE_F;
      float q  = rintf(v);                 // round-half-even, matches np.round; 0..31
      bits = (int8_t)q;
    }
    wk[idx] = bits;
  } else {
    int b = blockIdx.x - 2688;
    int i = threadIdx.x;
    for (int t = threadIdx.x; t < TT; t += 256) xs[t] = x[b * TT + t];
    __syncthreads();
    float w    = Wch[i];
    float beta = fminf(1.0f, fmaxf(0.0f, cbetas[i]));
    float mem  = 0.0f;
    for (int t = 0; t < TT; ++t) {
      float cur = __fmul_rn(xs[t], w);
      int   rs  = (mem > 1.0f);
      float t2  = __fadd_rn(__fmul_rn(beta, mem), cur);
      mem = rs ? __fsub_rn(t2, 1.0f) : t2;
      int spk = (mem > 1.0f);
      chs[(size_t)(t * BB + b) * IND + i] = (int8_t)spk;
    }
  }
}

// ---------------------------------------------------------------- fused layer: GEMM + LIF scan
// One block = (batch element b) x (64-col slice h0); b=blk&63 keeps the 8
// slice-blocks of a batch on one XCD. Per 64-t batch: 4-wave i8 MFMA from
// swizzled LDS (+1 ones-column MFMA -> row spike-count n, column-constant in
// D so each lane's acc4[i] IS n — no shuffle, no nbuf). Each wave converts its
// own acc to f32 cur IN THE EPILOGUE (f64 math parallel across 4 waves, off
// the serial wave) -> curbuf f32 in LDS -> barrier -> async next-A stage ->
// wave0 runs the bare np-exact fp32 chain (quarters of 16, 1-q lookahead).
// LDS: Bs+As+curbuf = 32K+32K+16K = 81920 B exactly -> 2 blocks/CU (K=512).
template<int K, bool LAST>
__global__ __launch_bounds__(256) void k_layer(const int8_t* __restrict__ A,
                                               const int8_t* __restrict__ Bw,
                                               const float* __restrict__ pbeta,
                                               float* __restrict__ spk_out,
                                               int8_t* __restrict__ s_out,
                                               float* __restrict__ mem_out) {
  constexpr int CH = K / 16;                 // 16-B chunks per row (32 or 16)
  __shared__ __align__(16) int8_t Bs[64 * K];
  __shared__ __align__(16) int8_t As[64 * K];
  __shared__ float curbuf[64][64];           // f32 cur, written by all 4 waves
  int tid = threadIdx.x, lane = tid & 63, w = tid >> 6;
  int b, h0;
  if (LAST) { b = blockIdx.x;      h0 = 0; }
  else      { b = blockIdx.x & 63; h0 = (blockIdx.x >> 6) * 64; }
  float beta = fminf(1.0f, fmaxf(0.0f, *pbeta));
  // stage B slice [64][K], XOR-swizzled (slot sl holds chunk (sl&~7)|((sl&7)^(row&7)))
#pragma unroll
  for (int i = 0; i < CH / 4; ++i) {
    int L = i * 256 + tid;
    int row = L / CH, sl = L % CH;
    int kg = (sl & ~7) | ((sl & 7) ^ (row & 7));
    load16_lds(Bw + (size_t)(h0 + row) * K + kg * 16, &Bs[(i * 256 + w * 64) * 16]);
  }
  // stage A batch 0 (rows r -> global row r*64+b)
#pragma unroll
  for (int i = 0; i < CH / 4; ++i) {
    int L = i * 256 + tid;
    int r = L / CH, sl = L % CH;
    int kg = (sl & ~7) | ((sl & 7) ^ (r & 7));
    load16_lds(A + ((size_t)r * 64 + b) * K + kg * 16, &As[(i * 256 + w * 64) * 16]);
  }
  __syncthreads();
  const double DSCALE = (double)SCALE_F;
  const double DWMIN  = (double)0.001f;
  float mem = 0.0f;
  int lr = lane & 15, lk = lane >> 4;
  int arow = w * 16 + lr;
  const i32x4 ones = {0x01010101, 0x01010101, 0x01010101, 0x01010101};
  for (int g = 0; g < 8; ++g) {
    i32x4 acc0 = {0,0,0,0}, acc1 = {0,0,0,0}, acc2 = {0,0,0,0}, acc3 = {0,0,0,0};
    i32x4 acc4 = {0,0,0,0};                  // row-sum column (n), column-constant
#pragma unroll
    for (int ks = 0; ks < K / 64; ++ks) {
      int kc = ks * 4 + lk;
      int s0 = (kc & ~7) | ((kc & 7) ^ (lr & 7));     // shared slot (arow&7==brow&7==lr&7)
      i32x4 av  = *(const i32x4*)&As[arow * K + s0 * 16];
      i32x4 bv0 = *(const i32x4*)&Bs[(0 * 16 + lr) * K + s0 * 16];
      i32x4 bv1 = *(const i32x4*)&Bs[(1 * 16 + lr) * K + s0 * 16];
      i32x4 bv2 = *(const i32x4*)&Bs[(2 * 16 + lr) * K + s0 * 16];
      i32x4 bv3 = *(const i32x4*)&Bs[(3 * 16 + lr) * K + s0 * 16];
      acc0 = __builtin_amdgcn_mfma_i32_16x16x64_i8(av, bv0, acc0, 0, 0, 0);
      acc1 = __builtin_amdgcn_mfma_i32_16x16x64_i8(av, bv1, acc1, 0, 0, 0);
      acc2 = __builtin_amdgcn_mfma_i32_16x16x64_i8(av, bv2, acc2, 0, 0, 0);
      acc3 = __builtin_amdgcn_mfma_i32_16x16x64_i8(av, bv3, acc3, 0, 0, 0);
      acc4 = __builtin_amdgcn_mfma_i32_16x16x64_i8(av, ones, acc4, 0, 0, 0);
    }
    // epilogue: cur = f32(f64(M)*DSCALE + f64(n)*DWMIN), per wave for its rows.
    // D layout: row = w*16 + lk*4 + i, col = cg*16 + lr (verified).
    int pr = w * 16 + lk * 4;
#pragma unroll
    for (int i = 0; i < 4; ++i) {
      double nd = (double)acc4[i] * DWMIN;
      curbuf[pr + i][ 0 + lr] = (float)((double)acc0[i] * DSCALE + nd);
      curbuf[pr + i][16 + lr] = (float)((double)acc1[i] * DSCALE + nd);
      curbuf[pr + i][32 + lr] = (float)((double)acc2[i] * DSCALE + nd);
      curbuf[pr + i][48 + lr] = (float)((double)acc3[i] * DSCALE + nd);
    }
    __syncthreads();                 // curbuf ready; As consumed
    // all waves: issue next A batch (async; drains at the trailing barrier)
    if (g < 7) {
#pragma unroll
      for (int i = 0; i < CH / 4; ++i) {
        int L = i * 256 + tid;
        int r = L / CH, sl = L % CH;
        int kg = (sl & ~7) | ((sl & 7) ^ (r & 7));
        int t = (g + 1) * 64 + r; if (t > 499) t = 499;
        load16_lds(A + ((size_t)t * 64 + b) * K + kg * 16, &As[(i * 256 + w * 64) * 16]);
      }
    }
    // wave0: bare np-exact fp32 chain, quarters of 16 with 1-quarter lookahead.
    if (w == 0) {
      float curA[16], curB[16];
#define LOADQ(dst, q)                                                         \
      { _Pragma("unroll") for (int r = 0; r < 16; ++r)                        \
          dst[r] = curbuf[(q) * 16 + r][lane]; }
#define CHAINQ(src, q)                                                        \
      { _Pragma("unroll") for (int r = 0; r < 16; ++r) {                      \
          int t = g * 64 + (q) * 16 + r;                                      \
          int   rs = (mem > 1.0f);                                            \
          float t2 = __fadd_rn(__fmul_rn(beta, mem), src[r]);                 \
          mem = rs ? __fsub_rn(t2, 1.0f) : t2;                                \
          int spk = (mem > 1.0f);                                             \
          if (t < 500) {                                                      \
            int row = t * 64 + b;                                             \
            if (!LAST) {                                                      \
              __builtin_nontemporal_store(spk ? 1.0f : 0.0f,                  \
                  &spk_out[(size_t)t * 32768 + (b << 9) + h0 + lane]);        \
              s_out[(size_t)row * 512 + h0 + lane] = (int8_t)spk;             \
            } else if (lane < OD) {                                           \
              __builtin_nontemporal_store(spk ? 1.0f : 0.0f,                  \
                  &spk_out[(size_t)t * (BB * OD) + b * OD + lane]);           \
              __builtin_nontemporal_store(mem,                                \
                  &mem_out[(size_t)t * (BB * OD) + b * OD + lane]);           \
            }                                                                 \
          } } }
      LOADQ(curA, 0)
      LOADQ(curB, 1)
      CHAINQ(curA, 0)
      LOADQ(curA, 2)
      CHAINQ(curB, 1)
      LOADQ(curB, 3)
      CHAINQ(curA, 2)
      CHAINQ(curB, 3)
#undef LOADQ
#undef CHAINQ
    }
    __syncthreads();                 // As[g+1] staged; curbuf free for overwrite
  }
}

// ---------------------------------------------------------------- launch (5 nodes, no memset)
extern "C" void kernel_launch(void* const* d_in, const int* in_sizes, int n_in,
                              void* d_out, int out_size, void* d_ws, size_t ws_size,
                              hipStream_t stream) {
  const float* x      = (const float*)d_in[0];
  const float* Wch    = (const float*)d_in[1];
  const float* W1     = (const float*)d_in[2];
  const float* W2     = (const float*)d_in[3];
  const float* W3     = (const float*)d_in[4];
  const float* W4     = (const float*)d_in[5];
  const float* cbetas = (const float*)d_in[6];
  const float* b1     = (const float*)d_in[7];
  const float* b2     = (const float*)d_in[8];
  const float* b3     = (const float*)d_in[9];
  const float* b4     = (const float*)d_in[10];

  uint8_t* ws = (uint8_t*)d_ws;
  int8_t*   wk1   = (int8_t*)(ws + 0);          // 512*256   = 131072
  int8_t*   wk2   = (int8_t*)(ws + 131072);     // 512*512   = 262144
  int8_t*   wk3   = (int8_t*)(ws + 393216);     // 262144
  int8_t*   wk4   = (int8_t*)(ws + 655360);     // 64*512    = 32768 -> 688128
  int8_t*   chs   = (int8_t*)(ws + 688128);     // 32000*256 = 8192000
  int8_t*   sbufA = (int8_t*)(ws + 8880128);    // 32000*512 = 16384000
  int8_t*   sbufB = (int8_t*)(ws + 25264128);   // -> ends 41648128

  float* out  = (float*)d_out;
  float* spk1 = out;                // 500*64*512
  float* spk2 = out + 16384000;
  float* spk3 = out + 32768000;
  float* spk4 = out + 49152000;     // 500*64*35
  float* mem4 = out + 50272000;

  // prep (blocks 0..2687) + cochlea (blocks 2688..2751), independent work
  k_prep_cochlea<<<2752, 256, 0, stream>>>(W1, W2, W3, W4, wk1, wk2, wk3, wk4,
                                           x, Wch, cbetas, chs);

  // fused layers: read buffer != write buffer
  k_layer<256, false><<<512, 256, 0, stream>>>(chs,   wk1, b1, spk1, sbufA, nullptr);
  k_layer<512, false><<<512, 256, 0, stream>>>(sbufA, wk2, b2, spk2, sbufB, nullptr);
  k_layer<512, false><<<512, 256, 0, stream>>>(sbufB, wk3, b3, spk3, sbufA, nullptr);
  k_layer<512, true ><<<64,  256, 0, stream>>>(sbufA, wk4, b4, spk4, nullptr, mem4);
}

// Round 13
// 343.536 us; speedup vs baseline: 2.0004x; 1.0271x over previous
//
#include <hip/hip_runtime.h>
#include <stdint.h>

#define TT   500
#define BB   64
#define IND  256
#define HD   512
#define OD   35

typedef __attribute__((ext_vector_type(4))) int i32x4;

// fp32 scale exactly as numpy computes it
#define SCALE_F ((float)((1.0 - 0.001) / 31.0))

__device__ __forceinline__ void load16_lds(const int8_t* g, int8_t* l) {
  __builtin_amdgcn_global_load_lds((const __attribute__((address_space(1))) void*)g,
                                   (__attribute__((address_space(3))) void*)l, 16, 0, 0);
}

// ---------------------------------------------------------------- prep + cochlea
// prep blocks (0..2687): weight quant. cochlea blocks (2688..2751): LIF scan.
// No spike-count outputs anywhere: consumers compute n via a ones-column MFMA.
__global__ __launch_bounds__(256) void k_prep_cochlea(const float* __restrict__ W1,
                                                      const float* __restrict__ W2,
                                                      const float* __restrict__ W3,
                                                      const float* __restrict__ W4,
                                                      int8_t* __restrict__ wk1,
                                                      int8_t* __restrict__ wk2,
                                                      int8_t* __restrict__ wk3,
                                                      int8_t* __restrict__ wk4,
                                                      const float* __restrict__ x,
                                                      const float* __restrict__ Wch,
                                                      const float* __restrict__ cbetas,
                                                      int8_t* __restrict__ chs) {
  __shared__ float xs[TT];
  if (blockIdx.x < 2688) {
    int id = blockIdx.x * 256 + threadIdx.x;
    const float* W; int8_t* wk; int idx, K, H;
    if (id < 131072)       { idx = id;          W = W1; wk = wk1; K = 256; H = 512; }
    else if (id < 393216)  { idx = id - 131072; W = W2; wk = wk2; K = 512; H = 512; }
    else if (id < 655360)  { idx = id - 393216; W = W3; wk = wk3; K = 512; H = 512; }
    else                   { idx = id - 655360; W = W4; wk = wk4; K = 512; H = 35;  }
    int h = idx / K;
    int k = idx - h * K;
    int8_t bits = 0;
    if (h < H) {
      float w  = W[h * K + k];
      float wc = fminf(1.0f, fmaxf(0.001f, w));
      float v  = (wc - 0.001f) / SCALE_F;
      float q  = rintf(v);                 // round-half-even, matches np.round; 0..31
      bits = (int8_t)q;
    }
    wk[idx] = bits;
  } else {
    int b = blockIdx.x - 2688;
    int i = threadIdx.x;
    for (int t = threadIdx.x; t < TT; t += 256) xs[t] = x[b * TT + t];
    __syncthreads();
    float w    = Wch[i];
    float beta = fminf(1.0f, fmaxf(0.0f, cbetas[i]));
    float mem  = 0.0f;
    for (int t = 0; t < TT; ++t) {
      float cur = __fmul_rn(xs[t], w);
      int   rs  = (mem > 1.0f);
      float t2  = __fadd_rn(__fmul_rn(beta, mem), cur);
      mem = rs ? __fsub_rn(t2, 1.0f) : t2;
      int spk = (mem > 1.0f);
      chs[(size_t)(t * BB + b) * IND + i] = (int8_t)spk;
    }
  }
}

// ---------------------------------------------------------------- fused layer: GEMM + LIF scan
// One block = (batch element b) x (64-col slice h0); b=blk&63 keeps the 8
// slice-blocks of a batch on one XCD. B-operand fragments are hoisted into
// REGISTERS once (breg[4][K/64], constexpr-indexed) — per-batch MFMA phase then
// issues only 8 A ds_reads/wave instead of 40 (LDS-pipe was the contended
// resource at 2 blocks/CU). Per 64-t batch: 4-wave i8 MFMA (+1 ones-column
// MFMA -> row spike-count n, column-constant in D) -> f64 cur in the epilogue
// (parallel across waves) -> curbuf f32 in LDS -> barrier -> async next-A
// stage -> wave0 bare fp32 LIF chain (quarters of 16, 1-q lookahead).
// LDS: Bs+As+curbuf = 32K+32K+16K = 81920 B exactly -> 2 blocks/CU (K=512).
template<int K, bool LAST>
__global__ __launch_bounds__(256, 2) void k_layer(const int8_t* __restrict__ A,
                                                  const int8_t* __restrict__ Bw,
                                                  const float* __restrict__ pbeta,
                                                  float* __restrict__ spk_out,
                                                  int8_t* __restrict__ s_out,
                                                  float* __restrict__ mem_out) {
  constexpr int CH = K / 16;                 // 16-B chunks per row (32 or 16)
  constexpr int KS = K / 64;                 // ks-steps (8 or 4)
  __shared__ __align__(16) int8_t Bs[64 * K];
  __shared__ __align__(16) int8_t As[64 * K];
  __shared__ float curbuf[64][64];           // f32 cur, written by all 4 waves
  int tid = threadIdx.x, lane = tid & 63, w = tid >> 6;
  int b, h0;
  if (LAST) { b = blockIdx.x;      h0 = 0; }
  else      { b = blockIdx.x & 63; h0 = (blockIdx.x >> 6) * 64; }
  float beta = fminf(1.0f, fmaxf(0.0f, *pbeta));
  // stage B slice [64][K], XOR-swizzled (slot sl holds chunk (sl&~7)|((sl&7)^(row&7)))
#pragma unroll
  for (int i = 0; i < CH / 4; ++i) {
    int L = i * 256 + tid;
    int row = L / CH, sl = L % CH;
    int kg = (sl & ~7) | ((sl & 7) ^ (row & 7));
    load16_lds(Bw + (size_t)(h0 + row) * K + kg * 16, &Bs[(i * 256 + w * 64) * 16]);
  }
  // stage A batch 0 (rows r -> global row r*64+b)
#pragma unroll
  for (int i = 0; i < CH / 4; ++i) {
    int L = i * 256 + tid;
    int r = L / CH, sl = L % CH;
    int kg = (sl & ~7) | ((sl & 7) ^ (r & 7));
    load16_lds(A + ((size_t)r * 64 + b) * K + kg * 16, &As[(i * 256 + w * 64) * 16]);
  }
  __syncthreads();
  const double DSCALE = (double)SCALE_F;
  const double DWMIN  = (double)0.001f;
  float mem = 0.0f;
  int lr = lane & 15, lk = lane >> 4;
  int arow = w * 16 + lr;
  // hoist B fragments into registers (one-time; constexpr-indexed -> VGPRs)
  i32x4 breg[4][KS];
#pragma unroll
  for (int cg = 0; cg < 4; ++cg)
#pragma unroll
    for (int ks = 0; ks < KS; ++ks) {
      int kc = ks * 4 + lk;
      int s0 = (kc & ~7) | ((kc & 7) ^ (lr & 7));
      breg[cg][ks] = *(const i32x4*)&Bs[(cg * 16 + lr) * K + s0 * 16];
    }
  const i32x4 ones = {0x01010101, 0x01010101, 0x01010101, 0x01010101};
  for (int g = 0; g < 8; ++g) {
    i32x4 acc0 = {0,0,0,0}, acc1 = {0,0,0,0}, acc2 = {0,0,0,0}, acc3 = {0,0,0,0};
    i32x4 acc4 = {0,0,0,0};                  // row-sum column (n), column-constant
#pragma unroll
    for (int ks = 0; ks < KS; ++ks) {
      int kc = ks * 4 + lk;
      int s0 = (kc & ~7) | ((kc & 7) ^ (lr & 7));     // shared slot (arow&7==lr&7)
      i32x4 av = *(const i32x4*)&As[arow * K + s0 * 16];
      acc0 = __builtin_amdgcn_mfma_i32_16x16x64_i8(av, breg[0][ks], acc0, 0, 0, 0);
      acc1 = __builtin_amdgcn_mfma_i32_16x16x64_i8(av, breg[1][ks], acc1, 0, 0, 0);
      acc2 = __builtin_amdgcn_mfma_i32_16x16x64_i8(av, breg[2][ks], acc2, 0, 0, 0);
      acc3 = __builtin_amdgcn_mfma_i32_16x16x64_i8(av, breg[3][ks], acc3, 0, 0, 0);
      acc4 = __builtin_amdgcn_mfma_i32_16x16x64_i8(av, ones, acc4, 0, 0, 0);
    }
    // epilogue: cur = f32(f64(M)*DSCALE + f64(n)*DWMIN), per wave for its rows.
    // D layout: row = w*16 + lk*4 + i, col = cg*16 + lr (verified).
    int pr = w * 16 + lk * 4;
#pragma unroll
    for (int i = 0; i < 4; ++i) {
      double nd = (double)acc4[i] * DWMIN;
      curbuf[pr + i][ 0 + lr] = (float)((double)acc0[i] * DSCALE + nd);
      curbuf[pr + i][16 + lr] = (float)((double)acc1[i] * DSCALE + nd);
      curbuf[pr + i][32 + lr] = (float)((double)acc2[i] * DSCALE + nd);
      curbuf[pr + i][48 + lr] = (float)((double)acc3[i] * DSCALE + nd);
    }
    __syncthreads();                 // curbuf ready; As consumed
    // all waves: issue next A batch (async; drains at the trailing barrier)
    if (g < 7) {
#pragma unroll
      for (int i = 0; i < CH / 4; ++i) {
        int L = i * 256 + tid;
        int r = L / CH, sl = L % CH;
        int kg = (sl & ~7) | ((sl & 7) ^ (r & 7));
        int t = (g + 1) * 64 + r; if (t > 499) t = 499;
        load16_lds(A + ((size_t)t * 64 + b) * K + kg * 16, &As[(i * 256 + w * 64) * 16]);
      }
    }
    // wave0: bare np-exact fp32 chain, quarters of 16 with 1-quarter lookahead.
    if (w == 0) {
      float curA[16], curB[16];
#define LOADQ(dst, q)                                                         \
      { _Pragma("unroll") for (int r = 0; r < 16; ++r)                        \
          dst[r] = curbuf[(q) * 16 + r][lane]; }
#define CHAINQ(src, q)                                                        \
      { _Pragma("unroll") for (int r = 0; r < 16; ++r) {                      \
          int t = g * 64 + (q) * 16 + r;                                      \
          int   rs = (mem > 1.0f);                                            \
          float t2 = __fadd_rn(__fmul_rn(beta, mem), src[r]);                 \
          mem = rs ? __fsub_rn(t2, 1.0f) : t2;                                \
          int spk = (mem > 1.0f);                                             \
          if (t < 500) {                                                      \
            int row = t * 64 + b;                                             \
            if (!LAST) {                                                      \
              __builtin_nontemporal_store(spk ? 1.0f : 0.0f,                  \
                  &spk_out[(size_t)t * 32768 + (b << 9) + h0 + lane]);        \
              s_out[(size_t)row * 512 + h0 + lane] = (int8_t)spk;             \
            } else if (lane < OD) {                                           \
              __builtin_nontemporal_store(spk ? 1.0f : 0.0f,                  \
                  &spk_out[(size_t)t * (BB * OD) + b * OD + lane]);           \
              __builtin_nontemporal_store(mem,                                \
                  &mem_out[(size_t)t * (BB * OD) + b * OD + lane]);           \
            }                                                                 \
          } } }
      LOADQ(curA, 0)
      LOADQ(curB, 1)
      CHAINQ(curA, 0)
      LOADQ(curA, 2)
      CHAINQ(curB, 1)
      LOADQ(curB, 3)
      CHAINQ(curA, 2)
      CHAINQ(curB, 3)
#undef LOADQ
#undef CHAINQ
    }
    __syncthreads();                 // As[g+1] staged; curbuf free for overwrite
  }
}

// ---------------------------------------------------------------- launch (5 nodes, no memset)
extern "C" void kernel_launch(void* const* d_in, const int* in_sizes, int n_in,
                              void* d_out, int out_size, void* d_ws, size_t ws_size,
                              hipStream_t stream) {
  const float* x      = (const float*)d_in[0];
  const float* Wch    = (const float*)d_in[1];
  const float* W1     = (const float*)d_in[2];
  const float* W2     = (const float*)d_in[3];
  const float* W3     = (const float*)d_in[4];
  const float* W4     = (const float*)d_in[5];
  const float* cbetas = (const float*)d_in[6];
  const float* b1     = (const float*)d_in[7];
  const float* b2     = (const float*)d_in[8];
  const float* b3     = (const float*)d_in[9];
  const float* b4     = (const float*)d_in[10];

  uint8_t* ws = (uint8_t*)d_ws;
  int8_t*   wk1   = (int8_t*)(ws + 0);          // 512*256   = 131072
  int8_t*   wk2   = (int8_t*)(ws + 131072);     // 512*512   = 262144
  int8_t*   wk3   = (int8_t*)(ws + 393216);     // 262144
  int8_t*   wk4   = (int8_t*)(ws + 655360);     // 64*512    = 32768 -> 688128
  int8_t*   chs   = (int8_t*)(ws + 688128);     // 32000*256 = 8192000
  int8_t*   sbufA = (int8_t*)(ws + 8880128);    // 32000*512 = 16384000
  int8_t*   sbufB = (int8_t*)(ws + 25264128);   // -> ends 41648128

  float* out  = (float*)d_out;
  float* spk1 = out;                // 500*64*512
  float* spk2 = out + 16384000;
  float* spk3 = out + 32768000;
  float* spk4 = out + 49152000;     // 500*64*35
  float* mem4 = out + 50272000;

  // prep (blocks 0..2687) + cochlea (blocks 2688..2751), independent work
  k_prep_cochlea<<<2752, 256, 0, stream>>>(W1, W2, W3, W4, wk1, wk2, wk3, wk4,
                                           x, Wch, cbetas, chs);

  // fused layers: read buffer != write buffer
  k_layer<256, false><<<512, 256, 0, stream>>>(chs,   wk1, b1, spk1, sbufA, nullptr);
  k_layer<512, false><<<512, 256, 0, stream>>>(sbufA, wk2, b2, spk2, sbufB, nullptr);
  k_layer<512, false><<<512, 256, 0, stream>>>(sbufB, wk3, b3, spk3, sbufA, nullptr);
  k_layer<512, true ><<<64,  256, 0, stream>>>(sbufA, wk4, b4, spk4, nullptr, mem4);
}

// Round 14
// 339.762 us; speedup vs baseline: 2.0227x; 1.0111x over previous
//
#include <hip/hip_runtime.h>
#include <stdint.h>

#define TT   500
#define BB   64
#define IND  256
#define HD   512
#define OD   35

typedef __attribute__((ext_vector_type(4))) int i32x4;

// fp32 scale exactly as numpy computes it
#define SCALE_F ((float)((1.0 - 0.001) / 31.0))

__device__ __forceinline__ void load16_lds(const int8_t* g, int8_t* l) {
  __builtin_amdgcn_global_load_lds((const __attribute__((address_space(1))) void*)g,
                                   (__attribute__((address_space(3))) void*)l, 16, 0, 0);
}

// ---------------------------------------------------------------- prep + cochlea
__global__ __launch_bounds__(256) void k_prep_cochlea(const float* __restrict__ W1,
                                                      const float* __restrict__ W2,
                                                      const float* __restrict__ W3,
                                                      const float* __restrict__ W4,
                                                      int8_t* __restrict__ wk1,
                                                      int8_t* __restrict__ wk2,
                                                      int8_t* __restrict__ wk3,
                                                      int8_t* __restrict__ wk4,
                                                      const float* __restrict__ x,
                                                      const float* __restrict__ Wch,
                                                      const float* __restrict__ cbetas,
                                                      int8_t* __restrict__ chs) {
  __shared__ float xs[TT];
  if (blockIdx.x < 2688) {
    int id = blockIdx.x * 256 + threadIdx.x;
    const float* W; int8_t* wk; int idx, K, H;
    if (id < 131072)       { idx = id;          W = W1; wk = wk1; K = 256; H = 512; }
    else if (id < 393216)  { idx = id - 131072; W = W2; wk = wk2; K = 512; H = 512; }
    else if (id < 655360)  { idx = id - 393216; W = W3; wk = wk3; K = 512; H = 512; }
    else                   { idx = id - 655360; W = W4; wk = wk4; K = 512; H = 35;  }
    int h = idx / K;
    int k = idx - h * K;
    int8_t bits = 0;
    if (h < H) {
      float w  = W[h * K + k];
      float wc = fminf(1.0f, fmaxf(0.001f, w));
      float v  = (wc - 0.001f) / SCALE_F;
      float q  = rintf(v);                 // round-half-even, matches np.round; 0..31
      bits = (int8_t)q;
    }
    wk[idx] = bits;
  } else {
    int b = blockIdx.x - 2688;
    int i = threadIdx.x;
    for (int t = threadIdx.x; t < TT; t += 256) xs[t] = x[b * TT + t];
    __syncthreads();
    float w    = Wch[i];
    float beta = fminf(1.0f, fmaxf(0.0f, cbetas[i]));
    float mem  = 0.0f;
    for (int t = 0; t < TT; ++t) {
      float cur = __fmul_rn(xs[t], w);
      int   rs  = (mem > 1.0f);
      float t2  = __fadd_rn(__fmul_rn(beta, mem), cur);
      mem = rs ? __fsub_rn(t2, 1.0f) : t2;
      int spk = (mem > 1.0f);
      chs[(size_t)(t * BB + b) * IND + i] = (int8_t)spk;
    }
  }
}

// A-staging, waves 1..3 only (wave0's VMEM queue stays stores-only).
// Slot swizzle: slot sl of row r holds global chunk (sl - 5r) & (CH-1), so the
// MFMA read (kc + 5*row) hits 16 distinct slots across a wave's 16 rows -> 2-way.
template<int K>
__device__ __forceinline__ void stage_a(const int8_t* __restrict__ A, int8_t* As,
                                        int b, int gnext, int w, int lane) {
  constexpr int CH = K / 16;
  if (w > 0) {
    constexpr int per = (CH + 2) / 3;
    int jlo = (w - 1) * per, jhi = jlo + per; if (jhi > CH) jhi = CH;
    for (int j = jlo; j < jhi; ++j) {
      int L = j * 64 + lane;
      int r = L / CH, sl = L % CH;
      int kg = (sl - 5 * r) & (CH - 1);
      int t = gnext * 64 + r; if (t > 499) t = 499;
      load16_lds(A + ((size_t)t * 64 + b) * K + kg * 16, &As[j * 1024]);
    }
  }
}

// ---------------------------------------------------------------- fused layer: GEMM + LIF scan
// One block = (batch b) x (64-col slice h0); b=blk&63 keeps slice-blocks of a
// batch on one XCD. B in registers (breg). Per 64-t batch: 4-wave i8 MFMA
// (+ones-column MFMA -> n) -> f64 cur epilogue -> curbuf -> raw barrier
// (lgkm only) -> waves1-3 stage next A / wave0 scans -> raw barrier
// (waves1-3 vmcnt(0), wave0 lgkm only — NT stores never drained in-loop).
template<int K, bool LAST>
__global__ __launch_bounds__(256, 2) void k_layer(const int8_t* __restrict__ A,
                                                  const int8_t* __restrict__ Bw,
                                                  const float* __restrict__ pbeta,
                                                  float* __restrict__ spk_out,
                                                  int8_t* __restrict__ s_out,
                                                  float* __restrict__ mem_out) {
  constexpr int CH = K / 16;                 // 16-B chunks per row (32 or 16)
  constexpr int KS = K / 64;                 // ks-steps (8 or 4)
  __shared__ __align__(16) int8_t Bs[64 * K];
  __shared__ __align__(16) int8_t As[64 * K];
  __shared__ float curbuf[64][64];           // f32 cur, written by all 4 waves
  int tid = threadIdx.x, lane = tid & 63, w = tid >> 6;
  int b, h0;
  if (LAST) { b = blockIdx.x;      h0 = 0; }
  else      { b = blockIdx.x & 63; h0 = (blockIdx.x >> 6) * 64; }
  float beta = fminf(1.0f, fmaxf(0.0f, *pbeta));
  // stage B slice [64][K] (one-time, all 256 threads, new swizzle)
#pragma unroll
  for (int i = 0; i < CH / 4; ++i) {
    int L = i * 256 + tid;
    int row = L / CH, sl = L % CH;
    int kg = (sl - 5 * row) & (CH - 1);
    load16_lds(Bw + (size_t)(h0 + row) * K + kg * 16, &Bs[(i * 256 + w * 64) * 16]);
  }
  stage_a<K>(A, As, b, 0, w, lane);          // A batch 0
  __syncthreads();                           // prologue: full drain (no stores yet)
  const double DSCALE = (double)SCALE_F;
  const double DWMIN  = (double)0.001f;
  float mem = 0.0f;
  int lr = lane & 15, lk = lane >> 4;
  int arow = w * 16 + lr;
  // hoist B fragments into registers (constexpr-indexed -> VGPRs)
  i32x4 breg[4][KS];
#pragma unroll
  for (int cg = 0; cg < 4; ++cg)
#pragma unroll
    for (int ks = 0; ks < KS; ++ks) {
      int row = cg * 16 + lr;
      int s0 = (ks * 4 + lk + 5 * row) & (CH - 1);
      breg[cg][ks] = *(const i32x4*)&Bs[row * K + s0 * 16];
    }
  const i32x4 ones = {0x01010101, 0x01010101, 0x01010101, 0x01010101};
  for (int g = 0; g < 8; ++g) {
    i32x4 acc0 = {0,0,0,0}, acc1 = {0,0,0,0}, acc2 = {0,0,0,0}, acc3 = {0,0,0,0};
    i32x4 acc4 = {0,0,0,0};                  // row-sum column (n), column-constant
#pragma unroll
    for (int ks = 0; ks < KS; ++ks) {
      int s0 = (ks * 4 + lk + 5 * arow) & (CH - 1);
      i32x4 av = *(const i32x4*)&As[arow * K + s0 * 16];
      acc0 = __builtin_amdgcn_mfma_i32_16x16x64_i8(av, breg[0][ks], acc0, 0, 0, 0);
      acc1 = __builtin_amdgcn_mfma_i32_16x16x64_i8(av, breg[1][ks], acc1, 0, 0, 0);
      acc2 = __builtin_amdgcn_mfma_i32_16x16x64_i8(av, breg[2][ks], acc2, 0, 0, 0);
      acc3 = __builtin_amdgcn_mfma_i32_16x16x64_i8(av, breg[3][ks], acc3, 0, 0, 0);
      acc4 = __builtin_amdgcn_mfma_i32_16x16x64_i8(av, ones, acc4, 0, 0, 0);
    }
    // epilogue: cur = f32(f64(M)*DSCALE + f64(n)*DWMIN); D row = w*16+lk*4+i, col = cg*16+lr
    int pr = w * 16 + lk * 4;
#pragma unroll
    for (int i = 0; i < 4; ++i) {
      double nd = (double)acc4[i] * DWMIN;
      curbuf[pr + i][ 0 + lr] = (float)((double)acc0[i] * DSCALE + nd);
      curbuf[pr + i][16 + lr] = (float)((double)acc1[i] * DSCALE + nd);
      curbuf[pr + i][32 + lr] = (float)((double)acc2[i] * DSCALE + nd);
      curbuf[pr + i][48 + lr] = (float)((double)acc3[i] * DSCALE + nd);
    }
    // B1: curbuf ready + all As reads complete. LDS-only drain — no store wait.
    __builtin_amdgcn_sched_barrier(0);
    asm volatile("s_waitcnt lgkmcnt(0)" ::: "memory");
    __builtin_amdgcn_s_barrier();
    __builtin_amdgcn_sched_barrier(0);
    // waves 1-3: stage next A batch (overwrites As; reads done per B1)
    if (g < 7) stage_a<K>(A, As, b, g + 1, w, lane);
    // wave0: bare np-exact fp32 chain, quarters of 16 with 1-quarter lookahead.
    if (w == 0) {
      float curA[16], curB[16];
#define LOADQ(dst, q)                                                         \
      { _Pragma("unroll") for (int r = 0; r < 16; ++r)                        \
          dst[r] = curbuf[(q) * 16 + r][lane]; }
#define CHAINQ(src, q)                                                        \
      { _Pragma("unroll") for (int r = 0; r < 16; ++r) {                      \
          int t = g * 64 + (q) * 16 + r;                                      \
          int   rs = (mem > 1.0f);                                            \
          float t2 = __fadd_rn(__fmul_rn(beta, mem), src[r]);                 \
          mem = rs ? __fsub_rn(t2, 1.0f) : t2;                                \
          int spk = (mem > 1.0f);                                             \
          if (t < 500) {                                                      \
            int row = t * 64 + b;                                             \
            if (!LAST) {                                                      \
              __builtin_nontemporal_store(spk ? 1.0f : 0.0f,                  \
                  &spk_out[(size_t)t * 32768 + (b << 9) + h0 + lane]);        \
              s_out[(size_t)row * 512 + h0 + lane] = (int8_t)spk;             \
            } else if (lane < OD) {                                           \
              __builtin_nontemporal_store(spk ? 1.0f : 0.0f,                  \
                  &spk_out[(size_t)t * (BB * OD) + b * OD + lane]);           \
              __builtin_nontemporal_store(mem,                                \
                  &mem_out[(size_t)t * (BB * OD) + b * OD + lane]);           \
            }                                                                 \
          } } }
      LOADQ(curA, 0)
      LOADQ(curB, 1)
      CHAINQ(curA, 0)
      LOADQ(curA, 2)
      CHAINQ(curB, 1)
      LOADQ(curB, 3)
      CHAINQ(curA, 2)
      CHAINQ(curB, 3)
#undef LOADQ
#undef CHAINQ
    }
    // B2: staging landed (waves1-3 vmcnt) + wave0's curbuf reads done.
    // Wave0's NT stores are NEVER drained inside the loop (T4 principle).
    __builtin_amdgcn_sched_barrier(0);
    if (w == 0) asm volatile("s_waitcnt lgkmcnt(0)" ::: "memory");
    else        asm volatile("s_waitcnt vmcnt(0) lgkmcnt(0)" ::: "memory");
    __builtin_amdgcn_s_barrier();
    __builtin_amdgcn_sched_barrier(0);
  }
}

// ---------------------------------------------------------------- launch (5 nodes, no memset)
extern "C" void kernel_launch(void* const* d_in, const int* in_sizes, int n_in,
                              void* d_out, int out_size, void* d_ws, size_t ws_size,
                              hipStream_t stream) {
  const float* x      = (const float*)d_in[0];
  const float* Wch    = (const float*)d_in[1];
  const float* W1     = (const float*)d_in[2];
  const float* W2     = (const float*)d_in[3];
  const float* W3     = (const float*)d_in[4];
  const float* W4     = (const float*)d_in[5];
  const float* cbetas = (const float*)d_in[6];
  const float* b1     = (const float*)d_in[7];
  const float* b2     = (const float*)d_in[8];
  const float* b3     = (const float*)d_in[9];
  const float* b4     = (const float*)d_in[10];

  uint8_t* ws = (uint8_t*)d_ws;
  int8_t*   wk1   = (int8_t*)(ws + 0);          // 512*256   = 131072
  int8_t*   wk2   = (int8_t*)(ws + 131072);     // 512*512   = 262144
  int8_t*   wk3   = (int8_t*)(ws + 393216);     // 262144
  int8_t*   wk4   = (int8_t*)(ws + 655360);     // 64*512    = 32768 -> 688128
  int8_t*   chs   = (int8_t*)(ws + 688128);     // 32000*256 = 8192000
  int8_t*   sbufA = (int8_t*)(ws + 8880128);    // 32000*512 = 16384000
  int8_t*   sbufB = (int8_t*)(ws + 25264128);   // -> ends 41648128

  float* out  = (float*)d_out;
  float* spk1 = out;                // 500*64*512
  float* spk2 = out + 16384000;
  float* spk3 = out + 32768000;
  float* spk4 = out + 49152000;     // 500*64*35
  float* mem4 = out + 50272000;

  // prep (blocks 0..2687) + cochlea (blocks 2688..2751), independent work
  k_prep_cochlea<<<2752, 256, 0, stream>>>(W1, W2, W3, W4, wk1, wk2, wk3, wk4,
                                           x, Wch, cbetas, chs);

  // fused layers: read buffer != write buffer
  k_layer<256, false><<<512, 256, 0, stream>>>(chs,   wk1, b1, spk1, sbufA, nullptr);
  k_layer<512, false><<<512, 256, 0, stream>>>(sbufA, wk2, b2, spk2, sbufB, nullptr);
  k_layer<512, false><<<512, 256, 0, stream>>>(sbufB, wk3, b3, spk3, sbufA, nullptr);
  k_layer<512, true ><<<64,  256, 0, stream>>>(sbufA, wk4, b4, spk4, nullptr, mem4);
}